// Round 1
// baseline (471.478 us; speedup 1.0000x reference)
//
#include <hip/hip_runtime.h>
#include <hip/hip_bf16.h>

#define BN 4
#define CN 320
#define NN 4096
#define EN 2
#define DKN 32
#define DVN 160

typedef __bf16 bf16;
typedef __bf16 bf16x8 __attribute__((ext_vector_type(8)));
typedef __bf16 bf16x4 __attribute__((ext_vector_type(4)));
typedef float f32x4 __attribute__((ext_vector_type(4)));

static __device__ __forceinline__ f32x4 mfma16(bf16x8 a, bf16x8 b, f32x4 c) {
  return __builtin_amdgcn_mfma_f32_16x16x32_bf16(a, b, c, 0, 0, 0);
}

// ---------------- kernel 1: cast/concat weights ----------------
// W_all rows: 0..63 = Q (e*32+dk), 64..127 = K, 128..447 = V (e*160+dv)
__global__ __launch_bounds__(256) void k_prep(
    const float* __restrict__ Wq, const float* __restrict__ bq,
    const float* __restrict__ Wk, const float* __restrict__ bk,
    const float* __restrict__ Wv, const float* __restrict__ bv,
    const float* __restrict__ Wm,
    bf16* __restrict__ W_all, bf16* __restrict__ Wm_bf, float* __restrict__ b_all) {
  int t = blockIdx.x * 256 + threadIdx.x;
  if (t < 448 * CN) {
    int r = t / CN;
    float v;
    if (r < 64) v = Wq[t];
    else if (r < 128) v = Wk[t - 64 * CN];
    else v = Wv[t - 128 * CN];
    W_all[t] = (bf16)v;
  }
  if (t < 320 * 320) Wm_bf[t] = (bf16)Wm[t];
  if (t < 448) {
    float v;
    if (t < 64) v = bq[t];
    else if (t < 128) v = bk[t - 64];
    else v = bv[t - 128];
    b_all[t] = v;
  }
}

// ---------------- kernel 2: x [b][c][n] f32 -> xT [b][n][c] bf16 ----------------
__global__ __launch_bounds__(256) void k_xt(const float* __restrict__ x, bf16* __restrict__ xT) {
  int t = blockIdx.x * 256 + threadIdx.x;  // B*N threads
  int b = t >> 12, n = t & (NN - 1);
  const float* xp = x + (size_t)b * CN * NN + n;
  bf16* op = xT + ((size_t)b * NN + n) * CN;
  for (int c0 = 0; c0 < CN; c0 += 8) {
    bf16x8 v;
#pragma unroll
    for (int j = 0; j < 8; j++) v[j] = (bf16)xp[(size_t)(c0 + j) * NN];
    *(bf16x8*)(op + c0) = v;
  }
}

// ---------------- kernel 3: projection GEMM ----------------
// D[row][n] = W_all[row][:] . xT[n][:] + bias. rows<128 -> QK f32, rows>=128 -> V bf16 [be][dv][n]
__global__ __launch_bounds__(256) void k_proj(
    const bf16* __restrict__ W_all, const float* __restrict__ b_all,
    const bf16* __restrict__ xT, float* __restrict__ QK, bf16* __restrict__ V) {
  int blk = blockIdx.x;            // b*448 + mt*16 + nb
  int b = blk / 448;
  int rem = blk - b * 448;
  int mt = rem >> 4, nb = rem & 15;
  int w = threadIdx.x >> 6, l = threadIdx.x & 63;
  int lg = l >> 4, lr = l & 15;
  int m0 = mt * 16;
  int n0 = nb * 256 + w * 64;
  f32x4 acc[4] = {};
  const bf16* wp = W_all + (m0 + lr) * CN + 8 * lg;
  const bf16* xp = xT + ((size_t)b * NN + n0 + lr) * CN + 8 * lg;
#pragma unroll 2
  for (int c0 = 0; c0 < CN; c0 += 32) {
    bf16x8 a = *(const bf16x8*)(wp + c0);
#pragma unroll
    for (int j = 0; j < 4; j++) {
      bf16x8 bb = *(const bf16x8*)(xp + j * 16 * CN + c0);
      acc[j] = mfma16(a, bb, acc[j]);
    }
  }
#pragma unroll
  for (int i = 0; i < 4; i++) {
    int row = m0 + 4 * lg + i;
    float bias = b_all[row];
    if (row < 128) {
      float* qk = QK + ((size_t)b * 128 + row) * NN + n0 + lr;
#pragma unroll
      for (int j = 0; j < 4; j++) qk[j * 16] = acc[j][i] + bias;
    } else {
      int rr = row - 128;
      int e = rr / 160, dv = rr - e * 160;
      bf16* vp = V + (((size_t)b * 2 + e) * 160 + dv) * NN + n0 + lr;
#pragma unroll
      for (int j = 0; j < 4; j++) vp[j * 16] = (bf16)(acc[j][i] + bias);
    }
  }
}

// ---------------- kernel 4: L2 normalize Q,K over dk; write [be][n][32] bf16 ----------------
__global__ __launch_bounds__(256) void k_norm(
    const float* __restrict__ QK, bf16* __restrict__ Qn, bf16* __restrict__ Kn) {
  int t = blockIdx.x * 256 + threadIdx.x;  // B*E*N
  int b = t >> 13, e = (t >> 12) & 1, n = t & (NN - 1);
  const float* qp = QK + ((size_t)b * 128 + e * 32) * NN + n;
  const float* kp = qp + (size_t)64 * NN;
  float q[32], k[32];
  float ssq = 0.f, ssk = 0.f;
#pragma unroll
  for (int d = 0; d < 32; d++) { float v = qp[(size_t)d * NN]; q[d] = v; ssq += v * v; }
#pragma unroll
  for (int d = 0; d < 32; d++) { float v = kp[(size_t)d * NN]; k[d] = v; ssk += v * v; }
  float sq = 1.0f / fmaxf(sqrtf(ssq), 1e-6f);
  float sk = 1.0f / fmaxf(sqrtf(ssk), 1e-6f);
  bf16* qo = Qn + ((size_t)(b * 2 + e) * NN + n) * 32;
  bf16* ko = Kn + ((size_t)(b * 2 + e) * NN + n) * 32;
#pragma unroll
  for (int d0 = 0; d0 < 32; d0 += 8) {
    bf16x8 vq, vk;
#pragma unroll
    for (int j = 0; j < 8; j++) {
      vq[j] = (bf16)(q[d0 + j] * sq);
      vk[j] = (bf16)(k[d0 + j] * sk);
    }
    *(bf16x8*)(qo + d0) = vq;
    *(bf16x8*)(ko + d0) = vk;
  }
}

// ---------------- kernel 5: attention ----------------
// Per wave: 32 queries. Swapped QK^T (mfma(K,Q) -> S^T) so P stays in registers
// as the PV A-fragment. Scores in [-1,1] => no max subtraction needed.
__global__ __launch_bounds__(256) void k_attn(
    const bf16* __restrict__ Qn, const bf16* __restrict__ Kn,
    const bf16* __restrict__ V, bf16* __restrict__ Rt) {
  __shared__ float smem[128];
  int blk = blockIdx.x;            // be*32 + qc
  int be = blk >> 5, qc = blk & 31;
  int w = threadIdx.x >> 6, l = threadIdx.x & 63;
  int lg = l >> 4, lr = l & 15;
  int qb = qc * 128 + w * 32;
  const bf16* qbase = Qn + ((size_t)be * NN + qb) * 32 + 8 * lg;
  bf16x8 qf0 = *(const bf16x8*)(qbase + lr * 32);
  bf16x8 qf1 = *(const bf16x8*)(qbase + (16 + lr) * 32);
  const bf16* kbase = Kn + (size_t)be * NN * 32 + 8 * lg;
  const bf16* vbase = V + ((size_t)be * 160 + lr) * NN + 4 * lg;
  f32x4 acc0[10] = {};
  f32x4 acc1[10] = {};
  float rs0 = 0.f, rs1 = 0.f;
  bf16x8 kf0 = *(const bf16x8*)(kbase + (size_t)lr * 32);
  bf16x8 kf1 = *(const bf16x8*)(kbase + (size_t)(16 + lr) * 32);
  for (int m0 = 0; m0 < NN; m0 += 32) {
    // V-fragment loads for this step, issued before the score MFMAs
    bf16x4 vlo[10], vhi[10];
#pragma unroll
    for (int vt = 0; vt < 10; vt++) {
      const bf16* vp = vbase + (size_t)vt * 16 * NN + m0;
      vlo[vt] = *(const bf16x4*)(vp);
      vhi[vt] = *(const bf16x4*)(vp + 16);
    }
    f32x4 zero = {};
    f32x4 s00 = mfma16(kf0, qf0, zero);  // S^T[m][q], m-half 0, q-subtile 0
    f32x4 s01 = mfma16(kf1, qf0, zero);
    f32x4 s10 = mfma16(kf0, qf1, zero);
    f32x4 s11 = mfma16(kf1, qf1, zero);
    // prefetch next K fragments
    if (m0 + 32 < NN) {
      kf0 = *(const bf16x8*)(kbase + (size_t)(m0 + 32 + lr) * 32);
      kf1 = *(const bf16x8*)(kbase + (size_t)(m0 + 48 + lr) * 32);
    }
    bf16x8 pf0, pf1;
#pragma unroll
    for (int i = 0; i < 4; i++) {
      float e00 = __expf(s00[i]), e01 = __expf(s01[i]);
      float e10 = __expf(s10[i]), e11 = __expf(s11[i]);
      rs0 += e00 + e01;
      rs1 += e10 + e11;
      pf0[i] = (bf16)e00; pf0[4 + i] = (bf16)e01;
      pf1[i] = (bf16)e10; pf1[4 + i] = (bf16)e11;
    }
#pragma unroll
    for (int vt = 0; vt < 10; vt++) {
      bf16x8 vf;
#pragma unroll
      for (int i = 0; i < 4; i++) { vf[i] = vlo[vt][i]; vf[4 + i] = vhi[vt][i]; }
      acc0[vt] = mfma16(pf0, vf, acc0[vt]);
      acc1[vt] = mfma16(pf1, vf, acc1[vt]);
    }
  }
  // rowsum: reduce partial sums across the 4 lane-groups (lanes with equal l&15)
  rs0 += __shfl_xor(rs0, 16); rs0 += __shfl_xor(rs0, 32);
  rs1 += __shfl_xor(rs1, 16); rs1 += __shfl_xor(rs1, 32);
  if (lg == 0) { smem[w * 32 + lr] = rs0; smem[w * 32 + 16 + lr] = rs1; }
  __syncthreads();
  int b = be >> 1, e = be & 1;
#pragma unroll
  for (int s = 0; s < 2; s++) {
    f32x4 rinv;
#pragma unroll
    for (int i = 0; i < 4; i++) rinv[i] = 1.0f / smem[w * 32 + s * 16 + 4 * lg + i];
#pragma unroll
    for (int vt = 0; vt < 10; vt++) {
#pragma unroll
      for (int i = 0; i < 4; i++) {
        float v = (s ? acc1[vt][i] : acc0[vt][i]) * rinv[i];
        int q = qb + 16 * s + 4 * lg + i;
        Rt[((size_t)b * NN + q) * 320 + e * 160 + vt * 16 + lr] = (bf16)v;
      }
    }
  }
}

// ---------------- kernel 6: merge GEMM + bias + residual ----------------
__global__ __launch_bounds__(256) void k_merge(
    const bf16* __restrict__ Wm_bf, const float* __restrict__ bm,
    const bf16* __restrict__ Rt, const float* __restrict__ x, float* __restrict__ out) {
  int blk = blockIdx.x;            // b*320 + ct*16 + nb
  int b = blk / 320;
  int rem = blk - b * 320;
  int ct = rem >> 4, nb = rem & 15;
  int w = threadIdx.x >> 6, l = threadIdx.x & 63;
  int lg = l >> 4, lr = l & 15;
  int c0 = ct * 16, n0 = nb * 256 + w * 64;
  f32x4 acc[4] = {};
  const bf16* ap = Wm_bf + (c0 + lr) * 320 + 8 * lg;
  const bf16* bp = Rt + ((size_t)b * NN + n0 + lr) * 320 + 8 * lg;
#pragma unroll 2
  for (int f0 = 0; f0 < 320; f0 += 32) {
    bf16x8 a = *(const bf16x8*)(ap + f0);
#pragma unroll
    for (int j = 0; j < 4; j++) {
      bf16x8 bb = *(const bf16x8*)(bp + j * 16 * 320 + f0);
      acc[j] = mfma16(a, bb, acc[j]);
    }
  }
#pragma unroll
  for (int i = 0; i < 4; i++) {
    int c = c0 + 4 * lg + i;
    float bias = bm[c];
    const float* xp = x + ((size_t)b * 320 + c) * NN + n0 + lr;
    float* op = out + ((size_t)b * 320 + c) * NN + n0 + lr;
#pragma unroll
    for (int j = 0; j < 4; j++) op[j * 16] = acc[j][i] + bias + xp[j * 16];
  }
}

extern "C" void kernel_launch(void* const* d_in, const int* in_sizes, int n_in,
                              void* d_out, int out_size, void* d_ws, size_t ws_size,
                              hipStream_t stream) {
  const float* x  = (const float*)d_in[0];
  const float* Wq = (const float*)d_in[1];
  const float* bq = (const float*)d_in[2];
  const float* Wk = (const float*)d_in[3];
  const float* bk = (const float*)d_in[4];
  const float* Wv = (const float*)d_in[5];
  const float* bv = (const float*)d_in[6];
  const float* Wm = (const float*)d_in[7];
  const float* bm = (const float*)d_in[8];
  float* out = (float*)d_out;
  char* ws = (char*)d_ws;
  // workspace layout (bytes, 256-aligned)
  bf16*  W_all = (bf16*)(ws + 0);           //  448*320*2      = 286720
  bf16*  Wm_bf = (bf16*)(ws + 286720);      //  320*320*2      = 204800 -> 491520
  float* b_all = (float*)(ws + 491520);     //  448*4          -> pad 493568
  bf16*  xT    = (bf16*)(ws + 493568);      //  4*4096*320*2   = 10485760 -> 10979328
  float* QK    = (float*)(ws + 10979328);   //  4*128*4096*4   = 8388608  -> 19367936
  bf16*  Qn    = (bf16*)(ws + 19367936);    //  8*4096*32*2    = 2097152  -> 21465088
  bf16*  Kn    = (bf16*)(ws + 21465088);    //  2097152        -> 23562240
  bf16*  Vb    = (bf16*)(ws + 23562240);    //  8*160*4096*2   = 10485760 -> 34048000
  bf16*  Rt    = (bf16*)(ws + 34048000);    //  4*4096*320*2   = 10485760 -> 44533760

  k_prep<<<560, 256, 0, stream>>>(Wq, bq, Wk, bk, Wv, bv, Wm, W_all, Wm_bf, b_all);
  k_xt<<<64, 256, 0, stream>>>(x, xT);
  k_proj<<<1792, 256, 0, stream>>>(W_all, b_all, xT, QK, Vb);
  k_norm<<<128, 256, 0, stream>>>(QK, Qn, Kn);
  k_attn<<<256, 256, 0, stream>>>(Qn, Kn, Vb, Rt);
  k_merge<<<1280, 256, 0, stream>>>(Wm_bf, bm, Rt, x, out);
}

// Round 6
// 466.348 us; speedup vs baseline: 1.0110x; 1.0110x over previous
//
#include <hip/hip_runtime.h>
#include <hip/hip_bf16.h>

#define BN 4
#define CN 320
#define NN 4096
#define EN 2
#define DKN 32
#define DVN 160

typedef __bf16 bf16;
typedef __bf16 bf16x8 __attribute__((ext_vector_type(8)));
typedef __bf16 bf16x4 __attribute__((ext_vector_type(4)));
typedef float f32x4 __attribute__((ext_vector_type(4)));

static __device__ __forceinline__ f32x4 mfma16(bf16x8 a, bf16x8 b, f32x4 c) {
  return __builtin_amdgcn_mfma_f32_16x16x32_bf16(a, b, c, 0, 0, 0);
}

// ---------------- kernel 1: cast/concat weights ----------------
// W_all rows: 0..63 = Q (e*32+dk), 64..127 = K, 128..447 = V (e*160+dv)
__global__ __launch_bounds__(256) void k_prep(
    const float* __restrict__ Wq, const float* __restrict__ bq,
    const float* __restrict__ Wk, const float* __restrict__ bk,
    const float* __restrict__ Wv, const float* __restrict__ bv,
    const float* __restrict__ Wm,
    bf16* __restrict__ W_all, bf16* __restrict__ Wm_bf, float* __restrict__ b_all) {
  int t = blockIdx.x * 256 + threadIdx.x;
  if (t < 448 * CN) {
    int r = t / CN;
    float v;
    if (r < 64) v = Wq[t];
    else if (r < 128) v = Wk[t - 64 * CN];
    else v = Wv[t - 128 * CN];
    W_all[t] = (bf16)v;
  }
  if (t < 320 * 320) Wm_bf[t] = (bf16)Wm[t];
  if (t < 448) {
    float v;
    if (t < 64) v = bq[t];
    else if (t < 128) v = bk[t - 64];
    else v = bv[t - 128];
    b_all[t] = v;
  }
}

// ---------------- kernel 2: x [b][c][n] f32 -> xT [b][n][c] bf16 ----------------
// grid = B * 40 * 16 = 2560 blocks; block covers (b, 8 channels, 256 n)
__global__ __launch_bounds__(256) void k_xt(const float* __restrict__ x, bf16* __restrict__ xT) {
  int blk = blockIdx.x;
  int b = blk / 640;
  int rem = blk - b * 640;
  int cc = rem >> 4;         // 0..39 (channel octet)
  int nb = rem & 15;
  int n = nb * 256 + threadIdx.x;
  const float* xp = x + ((size_t)b * CN + cc * 8) * NN + n;
  bf16x8 v;
#pragma unroll
  for (int j = 0; j < 8; j++) v[j] = (bf16)xp[(size_t)j * NN];
  *(bf16x8*)(xT + ((size_t)b * NN + n) * CN + cc * 8) = v;
}

// ---------------- kernel 3: projection GEMM ----------------
// D[row][n] = W_all[row][:] . xT[n][:] + bias. rows<128 -> QK f32, rows>=128 -> V bf16 [be][dv][n]
__global__ __launch_bounds__(256) void k_proj(
    const bf16* __restrict__ W_all, const float* __restrict__ b_all,
    const bf16* __restrict__ xT, float* __restrict__ QK, bf16* __restrict__ V) {
  int blk = blockIdx.x;            // b*448 + mt*16 + nb
  int b = blk / 448;
  int rem = blk - b * 448;
  int mt = rem >> 4, nb = rem & 15;
  int w = threadIdx.x >> 6, l = threadIdx.x & 63;
  int lg = l >> 4, lr = l & 15;
  int m0 = mt * 16;
  int n0 = nb * 256 + w * 64;
  f32x4 acc[4] = {};
  const bf16* wp = W_all + (m0 + lr) * CN + 8 * lg;
  const bf16* xp = xT + ((size_t)b * NN + n0 + lr) * CN + 8 * lg;
#pragma unroll 2
  for (int c0 = 0; c0 < CN; c0 += 32) {
    bf16x8 a = *(const bf16x8*)(wp + c0);
#pragma unroll
    for (int j = 0; j < 4; j++) {
      bf16x8 bb = *(const bf16x8*)(xp + j * 16 * CN + c0);
      acc[j] = mfma16(a, bb, acc[j]);
    }
  }
#pragma unroll
  for (int i = 0; i < 4; i++) {
    int row = m0 + 4 * lg + i;
    float bias = b_all[row];
    if (row < 128) {
      float* qk = QK + ((size_t)b * 128 + row) * NN + n0 + lr;
#pragma unroll
      for (int j = 0; j < 4; j++) qk[j * 16] = acc[j][i] + bias;
    } else {
      int rr = row - 128;
      int e = rr / 160, dv = rr - e * 160;
      bf16* vp = V + (((size_t)b * 2 + e) * 160 + dv) * NN + n0 + lr;
#pragma unroll
      for (int j = 0; j < 4; j++) vp[j * 16] = (bf16)(acc[j][i] + bias);
    }
  }
}

// ---------------- kernel 4: L2 normalize Q,K over dk; write [be][n][32] bf16 ----------------
// grid = 2*B*E*N / 256 = 256 blocks; first half of threads do Q, second K
__global__ __launch_bounds__(256) void k_norm(
    const float* __restrict__ QK, bf16* __restrict__ Qn, bf16* __restrict__ Kn) {
  int t = blockIdx.x * 256 + threadIdx.x;
  int isk = t >> 15;
  int r = t & 32767;
  int b = r >> 13, e = (r >> 12) & 1, n = r & (NN - 1);
  const float* p = QK + ((size_t)b * 128 + isk * 64 + e * 32) * NN + n;
  float v[32];
  float ss = 0.f;
#pragma unroll
  for (int d = 0; d < 32; d++) { float q = p[(size_t)d * NN]; v[d] = q; ss += q * q; }
  float s = 1.0f / fmaxf(sqrtf(ss), 1e-6f);
  bf16* o = (isk ? Kn : Qn) + ((size_t)(b * 2 + e) * NN + n) * 32;
#pragma unroll
  for (int d0 = 0; d0 < 32; d0 += 8) {
    bf16x8 vo;
#pragma unroll
    for (int j = 0; j < 8; j++) vo[j] = (bf16)(v[d0 + j] * s);
    *(bf16x8*)(o + d0) = vo;
  }
}

// ---------------- kernel 5: attention ----------------
// Block = (be, 32 queries), 4 waves each handling a disjoint quarter of the keys
// (split-K flash). Swapped QK^T keeps P in registers as the PV A-fragment;
// scores in [-1,1] => plain exp, no max tracking. Partials reduced via LDS tree.
__global__ __launch_bounds__(256) void k_attn(
    const bf16* __restrict__ Qn, const bf16* __restrict__ Kn,
    const bf16* __restrict__ V, bf16* __restrict__ Rt) {
  __shared__ float sbuf[64][83];   // stride 83: 2-way bank alias only (free)
  int blk = blockIdx.x;            // be*128 + qc
  int be = blk >> 7, qc = blk & 127;
  int w = threadIdx.x >> 6, l = threadIdx.x & 63;
  int lg = l >> 4, lr = l & 15;
  int qb = qc * 32;
  const bf16* qbase = Qn + ((size_t)be * NN + qb) * 32 + 8 * lg;
  bf16x8 qf0 = *(const bf16x8*)(qbase + lr * 32);
  bf16x8 qf1 = *(const bf16x8*)(qbase + (16 + lr) * 32);
  const bf16* kbase = Kn + (size_t)be * NN * 32 + 8 * lg;
  const bf16* vbase = V + ((size_t)be * 160 + lr) * NN + 4 * lg;
  int mstart = w * (NN / 4), mend = mstart + (NN / 4);
  f32x4 acc0[10] = {};
  f32x4 acc1[10] = {};
  float rs0 = 0.f, rs1 = 0.f;
  bf16x8 kf0 = *(const bf16x8*)(kbase + (size_t)(mstart + lr) * 32);
  bf16x8 kf1 = *(const bf16x8*)(kbase + (size_t)(mstart + 16 + lr) * 32);
  for (int m0 = mstart; m0 < mend; m0 += 32) {
    // V-fragment loads for this step, issued before the score MFMAs
    bf16x4 vlo[10], vhi[10];
#pragma unroll
    for (int vt = 0; vt < 10; vt++) {
      const bf16* vp = vbase + (size_t)vt * 16 * NN + m0;
      vlo[vt] = *(const bf16x4*)(vp);
      vhi[vt] = *(const bf16x4*)(vp + 16);
    }
    f32x4 zero = {};
    f32x4 s00 = mfma16(kf0, qf0, zero);  // S^T[m][q], m-half 0, q-subtile 0
    f32x4 s01 = mfma16(kf1, qf0, zero);
    f32x4 s10 = mfma16(kf0, qf1, zero);
    f32x4 s11 = mfma16(kf1, qf1, zero);
    // prefetch next K fragments
    if (m0 + 32 < mend) {
      kf0 = *(const bf16x8*)(kbase + (size_t)(m0 + 32 + lr) * 32);
      kf1 = *(const bf16x8*)(kbase + (size_t)(m0 + 48 + lr) * 32);
    }
    bf16x8 pf0, pf1;
#pragma unroll
    for (int i = 0; i < 4; i++) {
      float e00 = __expf(s00[i]), e01 = __expf(s01[i]);
      float e10 = __expf(s10[i]), e11 = __expf(s11[i]);
      rs0 += e00 + e01;
      rs1 += e10 + e11;
      pf0[i] = (bf16)e00; pf0[4 + i] = (bf16)e01;
      pf1[i] = (bf16)e10; pf1[4 + i] = (bf16)e11;
    }
#pragma unroll
    for (int vt = 0; vt < 10; vt++) {
      bf16x8 vf;
#pragma unroll
      for (int i = 0; i < 4; i++) { vf[i] = vlo[vt][i]; vf[4 + i] = vhi[vt][i]; }
      acc0[vt] = mfma16(pf0, vf, acc0[vt]);
      acc1[vt] = mfma16(pf1, vf, acc1[vt]);
    }
  }
  // cross-wave reduction of partial numerators + rowsums into wave 0
  for (int r = 1; r < 4; ++r) {
    if (w == r) {
      float* p = &sbuf[l][0];
#pragma unroll
      for (int vt = 0; vt < 10; vt++)
#pragma unroll
        for (int i = 0; i < 4; i++) {
          p[vt * 4 + i] = acc0[vt][i];
          p[40 + vt * 4 + i] = acc1[vt][i];
        }
      p[80] = rs0; p[81] = rs1;
    }
    __syncthreads();
    if (w == 0) {
      const float* p = &sbuf[l][0];
#pragma unroll
      for (int vt = 0; vt < 10; vt++)
#pragma unroll
        for (int i = 0; i < 4; i++) {
          acc0[vt][i] += p[vt * 4 + i];
          acc1[vt][i] += p[40 + vt * 4 + i];
        }
      rs0 += p[80]; rs1 += p[81];
    }
    __syncthreads();
  }
  if (w == 0) {
    // complete the rowsums across the 4 lane-groups, then broadcast in-wave
    rs0 += __shfl_xor(rs0, 16); rs0 += __shfl_xor(rs0, 32);
    rs1 += __shfl_xor(rs1, 16); rs1 += __shfl_xor(rs1, 32);
    f32x4 rinv0, rinv1;
#pragma unroll
    for (int i = 0; i < 4; i++) {
      rinv0[i] = 1.0f / __shfl(rs0, 4 * lg + i);
      rinv1[i] = 1.0f / __shfl(rs1, 4 * lg + i);
    }
    int b = be >> 1, e = be & 1;
#pragma unroll
    for (int vt = 0; vt < 10; vt++) {
#pragma unroll
      for (int i = 0; i < 4; i++) {
        int q0 = qb + 4 * lg + i;
        int q1 = qb + 16 + 4 * lg + i;
        Rt[((size_t)b * NN + q0) * 320 + e * 160 + vt * 16 + lr] = (bf16)(acc0[vt][i] * rinv0[i]);
        Rt[((size_t)b * NN + q1) * 320 + e * 160 + vt * 16 + lr] = (bf16)(acc1[vt][i] * rinv1[i]);
      }
    }
  }
}

// ---------------- kernel 6: merge GEMM + bias + residual ----------------
__global__ __launch_bounds__(256) void k_merge(
    const bf16* __restrict__ Wm_bf, const float* __restrict__ bm,
    const bf16* __restrict__ Rt, const float* __restrict__ x, float* __restrict__ out) {
  int blk = blockIdx.x;            // b*320 + ct*16 + nb
  int b = blk / 320;
  int rem = blk - b * 320;
  int ct = rem >> 4, nb = rem & 15;
  int w = threadIdx.x >> 6, l = threadIdx.x & 63;
  int lg = l >> 4, lr = l & 15;
  int c0 = ct * 16, n0 = nb * 256 + w * 64;
  f32x4 acc[4] = {};
  const bf16* ap = Wm_bf + (c0 + lr) * 320 + 8 * lg;
  const bf16* bp = Rt + ((size_t)b * NN + n0 + lr) * 320 + 8 * lg;
#pragma unroll 2
  for (int f0 = 0; f0 < 320; f0 += 32) {
    bf16x8 a = *(const bf16x8*)(ap + f0);
#pragma unroll
    for (int j = 0; j < 4; j++) {
      bf16x8 bb = *(const bf16x8*)(bp + j * 16 * 320 + f0);
      acc[j] = mfma16(a, bb, acc[j]);
    }
  }
#pragma unroll
  for (int i = 0; i < 4; i++) {
    int c = c0 + 4 * lg + i;
    float bias = bm[c];
    const float* xp = x + ((size_t)b * 320 + c) * NN + n0 + lr;
    float* op = out + ((size_t)b * 320 + c) * NN + n0 + lr;
#pragma unroll
    for (int j = 0; j < 4; j++) op[j * 16] = acc[j][i] + bias + xp[j * 16];
  }
}

extern "C" void kernel_launch(void* const* d_in, const int* in_sizes, int n_in,
                              void* d_out, int out_size, void* d_ws, size_t ws_size,
                              hipStream_t stream) {
  const float* x  = (const float*)d_in[0];
  const float* Wq = (const float*)d_in[1];
  const float* bq = (const float*)d_in[2];
  const float* Wk = (const float*)d_in[3];
  const float* bk = (const float*)d_in[4];
  const float* Wv = (const float*)d_in[5];
  const float* bv = (const float*)d_in[6];
  const float* Wm = (const float*)d_in[7];
  const float* bm = (const float*)d_in[8];
  float* out = (float*)d_out;
  char* ws = (char*)d_ws;
  // workspace layout (bytes, 256-aligned)
  bf16*  W_all = (bf16*)(ws + 0);           //  448*320*2      = 286720
  bf16*  Wm_bf = (bf16*)(ws + 286720);      //  320*320*2      = 204800 -> 491520
  float* b_all = (float*)(ws + 491520);     //  448*4          -> pad 493568
  bf16*  xT    = (bf16*)(ws + 493568);      //  4*4096*320*2   = 10485760 -> 10979328
  float* QK    = (float*)(ws + 10979328);   //  4*128*4096*4   = 8388608  -> 19367936
  bf16*  Qn    = (bf16*)(ws + 19367936);    //  8*4096*32*2    = 2097152  -> 21465088
  bf16*  Kn    = (bf16*)(ws + 21465088);    //  2097152        -> 23562240
  bf16*  Vb    = (bf16*)(ws + 23562240);    //  8*160*4096*2   = 10485760 -> 34048000
  bf16*  Rt    = (bf16*)(ws + 34048000);    //  4*4096*320*2   = 10485760 -> 44533760

  k_prep<<<560, 256, 0, stream>>>(Wq, bq, Wk, bk, Wv, bv, Wm, W_all, Wm_bf, b_all);
  k_xt<<<2560, 256, 0, stream>>>(x, xT);
  k_proj<<<1792, 256, 0, stream>>>(W_all, b_all, xT, QK, Vb);
  k_norm<<<256, 256, 0, stream>>>(QK, Qn, Kn);
  k_attn<<<1024, 256, 0, stream>>>(Qn, Kn, Vb, Rt);
  k_merge<<<1280, 256, 0, stream>>>(Wm_bf, bm, Rt, x, out);
}

// Round 9
// 235.076 us; speedup vs baseline: 2.0056x; 1.9838x over previous
//
#include <hip/hip_runtime.h>
#include <hip/hip_bf16.h>

#define BN 4
#define CN 320
#define NN 4096
#define EN 2
#define DKN 32
#define DVN 160

typedef __bf16 bf16;
typedef __bf16 bf16x8 __attribute__((ext_vector_type(8)));
typedef __bf16 bf16x4 __attribute__((ext_vector_type(4)));
typedef float f32x4 __attribute__((ext_vector_type(4)));

static __device__ __forceinline__ f32x4 mfma16(bf16x8 a, bf16x8 b, f32x4 c) {
  return __builtin_amdgcn_mfma_f32_16x16x32_bf16(a, b, c, 0, 0, 0);
}

// V is stored in "cell" (MFMA-fragment) order:
//   cell(be, T, vt, g, lr) = 8 bf16 = V[dv=vt*16+lr][keys 32T+{4g..4g+3, 16+4g..16+4g+3}]
//   element index inside cell: e = h*4+i  <->  key = 32T + 16h + 4g + i
//   linear: Vc[ ((((be*128+T)*10+vt)*4+g)*16 + lr)*8 + e ]
// so that in k_attn, lane l = g*16+lr reads its whole fragment as ONE contiguous
// bf16x8 at (base + l*8): a 1KB fully-coalesced wave load.

// ---------------- kernel 1: cast/concat weights ----------------
// W_all rows: 0..63 = Q (e*32+dk), 64..127 = K, 128..447 = V (e*160+dv)
__global__ __launch_bounds__(256) void k_prep(
    const float* __restrict__ Wq, const float* __restrict__ bq,
    const float* __restrict__ Wk, const float* __restrict__ bk,
    const float* __restrict__ Wv, const float* __restrict__ bv,
    const float* __restrict__ Wm,
    bf16* __restrict__ W_all, bf16* __restrict__ Wm_bf, float* __restrict__ b_all) {
  int t = blockIdx.x * 256 + threadIdx.x;
  if (t < 448 * CN) {
    int r = t / CN;
    float v;
    if (r < 64) v = Wq[t];
    else if (r < 128) v = Wk[t - 64 * CN];
    else v = Wv[t - 128 * CN];
    W_all[t] = (bf16)v;
  }
  if (t < 320 * 320) Wm_bf[t] = (bf16)Wm[t];
  if (t < 448) {
    float v;
    if (t < 64) v = bq[t];
    else if (t < 128) v = bk[t - 64];
    else v = bv[t - 128];
    b_all[t] = v;
  }
}

// ---------------- kernel 2: x [b][c][n] f32 -> xT [b][n][c] bf16 ----------------
__global__ __launch_bounds__(256) void k_xt(const float* __restrict__ x, bf16* __restrict__ xT) {
  int blk = blockIdx.x;
  int b = blk / 640;
  int rem = blk - b * 640;
  int cc = rem >> 4;         // 0..39 (channel octet)
  int nb = rem & 15;
  int n = nb * 256 + threadIdx.x;
  const float* xp = x + ((size_t)b * CN + cc * 8) * NN + n;
  bf16x8 v;
#pragma unroll
  for (int j = 0; j < 8; j++) v[j] = (bf16)xp[(size_t)j * NN];
  *(bf16x8*)(xT + ((size_t)b * NN + n) * CN + cc * 8) = v;
}

// ---------------- kernel 3: projection GEMM ----------------
// rows<128 -> QK f32 [b][row][n]; rows>=128 -> V bf16 in cell order (see above)
__global__ __launch_bounds__(256) void k_proj(
    const bf16* __restrict__ W_all, const float* __restrict__ b_all,
    const bf16* __restrict__ xT, float* __restrict__ QK, bf16* __restrict__ Vc) {
  int blk = blockIdx.x;            // b*448 + mt*16 + nb
  int b = blk / 448;
  int rem = blk - b * 448;
  int mt = rem >> 4, nb = rem & 15;
  int w = threadIdx.x >> 6, l = threadIdx.x & 63;
  int lg = l >> 4, lr = l & 15;
  int m0 = mt * 16;
  int n0 = nb * 256 + w * 64;
  f32x4 acc[4] = {};
  const bf16* wp = W_all + (m0 + lr) * CN + 8 * lg;
  const bf16* xp = xT + ((size_t)b * NN + n0 + lr) * CN + 8 * lg;
#pragma unroll 2
  for (int c0 = 0; c0 < CN; c0 += 32) {
    bf16x8 a = *(const bf16x8*)(wp + c0);
#pragma unroll
    for (int j = 0; j < 4; j++) {
      bf16x8 bb = *(const bf16x8*)(xp + j * 16 * CN + c0);
      acc[j] = mfma16(a, bb, acc[j]);
    }
  }
#pragma unroll
  for (int i = 0; i < 4; i++) {
    int row = m0 + 4 * lg + i;
    float bias = b_all[row];
    if (row < 128) {
      float* qk = QK + ((size_t)b * 128 + row) * NN + n0 + lr;
#pragma unroll
      for (int j = 0; j < 4; j++) qk[j * 16] = acc[j][i] + bias;
    } else {
      int rr = row - 128;
      int e = rr / 160, dvl = rr - e * 160;
      int vt = dvl >> 4, lrc = dvl & 15;
      size_t beI = (size_t)(b * 2 + e);
#pragma unroll
      for (int j = 0; j < 4; j++) {
        int key = n0 + j * 16 + lr;
        int T = key >> 5, h = (key >> 4) & 1, g = (key >> 2) & 3, ic = key & 3;
        Vc[(((beI * 128 + T) * 10 + vt) * 4 + g) * 128 + lrc * 8 + h * 4 + ic] =
            (bf16)(acc[j][i] + bias);
      }
    }
  }
}

// ---------------- kernel 4: L2 normalize Q,K over dk; write [be][n][32] bf16 ----------------
__global__ __launch_bounds__(256) void k_norm(
    const float* __restrict__ QK, bf16* __restrict__ Qn, bf16* __restrict__ Kn) {
  int t = blockIdx.x * 256 + threadIdx.x;
  int isk = t >> 15;
  int r = t & 32767;
  int b = r >> 13, e = (r >> 12) & 1, n = r & (NN - 1);
  const float* p = QK + ((size_t)b * 128 + isk * 64 + e * 32) * NN + n;
  float v[32];
  float ss = 0.f;
#pragma unroll
  for (int d = 0; d < 32; d++) { float q = p[(size_t)d * NN]; v[d] = q; ss += q * q; }
  float s = 1.0f / fmaxf(sqrtf(ss), 1e-6f);
  bf16* o = (isk ? Kn : Qn) + ((size_t)(b * 2 + e) * NN + n) * 32;
#pragma unroll
  for (int d0 = 0; d0 < 32; d0 += 8) {
    bf16x8 vo;
#pragma unroll
    for (int j = 0; j < 8; j++) vo[j] = (bf16)(v[d0 + j] * s);
    *(bf16x8*)(o + d0) = vo;
  }
}

// ---------------- kernel 5: attention ----------------
// Block = (be, 32 queries), 4 waves each on a disjoint key-quarter (split-K flash).
// Swapped QK^T keeps P in registers as the PV A-fragment; V is pre-arranged in
// cell order so each V fragment is ONE contiguous bf16x8 per lane (1KB/wave load).
__global__ __launch_bounds__(256) void k_attn(
    const bf16* __restrict__ Qn, const bf16* __restrict__ Kn,
    const bf16* __restrict__ Vc, bf16* __restrict__ Rt) {
  __shared__ float sbuf[64][83];   // stride 83: 2-way bank alias only (free)
  int blk = blockIdx.x;            // be*128 + qc
  int be = blk >> 7, qc = blk & 127;
  int w = threadIdx.x >> 6, l = threadIdx.x & 63;
  int lg = l >> 4, lr = l & 15;
  int qb = qc * 32;
  const bf16* qbase = Qn + ((size_t)be * NN + qb) * 32 + 8 * lg;
  bf16x8 qf0 = *(const bf16x8*)(qbase + lr * 32);
  bf16x8 qf1 = *(const bf16x8*)(qbase + (16 + lr) * 32);
  const bf16* kbase = Kn + (size_t)be * NN * 32 + 8 * lg;
  const bf16* vbase = Vc + (size_t)be * (128 * 10 * 512) + (size_t)l * 8;
  int mstart = w * (NN / 4), mend = mstart + (NN / 4);
  f32x4 acc0[10] = {};
  f32x4 acc1[10] = {};
  float rs0 = 0.f, rs1 = 0.f;
  bf16x8 kf0 = *(const bf16x8*)(kbase + (size_t)(mstart + lr) * 32);
  bf16x8 kf1 = *(const bf16x8*)(kbase + (size_t)(mstart + 16 + lr) * 32);
  for (int m0 = mstart; m0 < mend; m0 += 32) {
    // V fragments for this 32-key tile: 10 contiguous 16B/lane loads
    const bf16* vp = vbase + (size_t)(m0 >> 5) * (10 * 512);
    bf16x8 vf[10];
#pragma unroll
    for (int vt = 0; vt < 10; vt++) vf[vt] = *(const bf16x8*)(vp + vt * 512);
    f32x4 zero = {};
    f32x4 s00 = mfma16(kf0, qf0, zero);  // S^T[m][q], m-half 0, q-subtile 0
    f32x4 s01 = mfma16(kf1, qf0, zero);
    f32x4 s10 = mfma16(kf0, qf1, zero);
    f32x4 s11 = mfma16(kf1, qf1, zero);
    // prefetch next K fragments
    if (m0 + 32 < mend) {
      kf0 = *(const bf16x8*)(kbase + (size_t)(m0 + 32 + lr) * 32);
      kf1 = *(const bf16x8*)(kbase + (size_t)(m0 + 48 + lr) * 32);
    }
    bf16x8 pf0, pf1;
#pragma unroll
    for (int i = 0; i < 4; i++) {
      float e00 = __expf(s00[i]), e01 = __expf(s01[i]);
      float e10 = __expf(s10[i]), e11 = __expf(s11[i]);
      rs0 += e00 + e01;
      rs1 += e10 + e11;
      pf0[i] = (bf16)e00; pf0[4 + i] = (bf16)e01;
      pf1[i] = (bf16)e10; pf1[4 + i] = (bf16)e11;
    }
#pragma unroll
    for (int vt = 0; vt < 10; vt++) {
      acc0[vt] = mfma16(pf0, vf[vt], acc0[vt]);
      acc1[vt] = mfma16(pf1, vf[vt], acc1[vt]);
    }
  }
  // cross-wave reduction of partial numerators + rowsums into wave 0
  for (int r = 1; r < 4; ++r) {
    if (w == r) {
      float* p = &sbuf[l][0];
#pragma unroll
      for (int vt = 0; vt < 10; vt++)
#pragma unroll
        for (int i = 0; i < 4; i++) {
          p[vt * 4 + i] = acc0[vt][i];
          p[40 + vt * 4 + i] = acc1[vt][i];
        }
      p[80] = rs0; p[81] = rs1;
    }
    __syncthreads();
    if (w == 0) {
      const float* p = &sbuf[l][0];
#pragma unroll
      for (int vt = 0; vt < 10; vt++)
#pragma unroll
        for (int i = 0; i < 4; i++) {
          acc0[vt][i] += p[vt * 4 + i];
          acc1[vt][i] += p[40 + vt * 4 + i];
        }
      rs0 += p[80]; rs1 += p[81];
    }
    __syncthreads();
  }
  if (w == 0) {
    // complete the rowsums across the 4 lane-groups, then broadcast in-wave
    rs0 += __shfl_xor(rs0, 16); rs0 += __shfl_xor(rs0, 32);
    rs1 += __shfl_xor(rs1, 16); rs1 += __shfl_xor(rs1, 32);
    f32x4 rinv0, rinv1;
#pragma unroll
    for (int i = 0; i < 4; i++) {
      rinv0[i] = 1.0f / __shfl(rs0, 4 * lg + i);
      rinv1[i] = 1.0f / __shfl(rs1, 4 * lg + i);
    }
    int b = be >> 1, e = be & 1;
#pragma unroll
    for (int vt = 0; vt < 10; vt++) {
#pragma unroll
      for (int i = 0; i < 4; i++) {
        int q0 = qb + 4 * lg + i;
        int q1 = qb + 16 + 4 * lg + i;
        Rt[((size_t)b * NN + q0) * 320 + e * 160 + vt * 16 + lr] = (bf16)(acc0[vt][i] * rinv0[i]);
        Rt[((size_t)b * NN + q1) * 320 + e * 160 + vt * 16 + lr] = (bf16)(acc1[vt][i] * rinv1[i]);
      }
    }
  }
}

// ---------------- kernel 6: merge GEMM + bias + residual ----------------
__global__ __launch_bounds__(256) void k_merge(
    const bf16* __restrict__ Wm_bf, const float* __restrict__ bm,
    const bf16* __restrict__ Rt, const float* __restrict__ x, float* __restrict__ out) {
  int blk = blockIdx.x;            // b*320 + ct*16 + nb
  int b = blk / 320;
  int rem = blk - b * 320;
  int ct = rem >> 4, nb = rem & 15;
  int w = threadIdx.x >> 6, l = threadIdx.x & 63;
  int lg = l >> 4, lr = l & 15;
  int c0 = ct * 16, n0 = nb * 256 + w * 64;
  f32x4 acc[4] = {};
  const bf16* ap = Wm_bf + (c0 + lr) * 320 + 8 * lg;
  const bf16* bp = Rt + ((size_t)b * NN + n0 + lr) * 320 + 8 * lg;
#pragma unroll 2
  for (int f0 = 0; f0 < 320; f0 += 32) {
    bf16x8 a = *(const bf16x8*)(ap + f0);
#pragma unroll
    for (int j = 0; j < 4; j++) {
      bf16x8 bb = *(const bf16x8*)(bp + j * 16 * 320 + f0);
      acc[j] = mfma16(a, bb, acc[j]);
    }
  }
#pragma unroll
  for (int i = 0; i < 4; i++) {
    int c = c0 + 4 * lg + i;
    float bias = bm[c];
    const float* xp = x + ((size_t)b * 320 + c) * NN + n0 + lr;
    float* op = out + ((size_t)b * 320 + c) * NN + n0 + lr;
#pragma unroll
    for (int j = 0; j < 4; j++) op[j * 16] = acc[j][i] + bias + xp[j * 16];
  }
}

extern "C" void kernel_launch(void* const* d_in, const int* in_sizes, int n_in,
                              void* d_out, int out_size, void* d_ws, size_t ws_size,
                              hipStream_t stream) {
  const float* x  = (const float*)d_in[0];
  const float* Wq = (const float*)d_in[1];
  const float* bq = (const float*)d_in[2];
  const float* Wk = (const float*)d_in[3];
  const float* bk = (const float*)d_in[4];
  const float* Wv = (const float*)d_in[5];
  const float* bv = (const float*)d_in[6];
  const float* Wm = (const float*)d_in[7];
  const float* bm = (const float*)d_in[8];
  float* out = (float*)d_out;
  char* ws = (char*)d_ws;
  // workspace layout (bytes, 256-aligned)
  bf16*  W_all = (bf16*)(ws + 0);           //  448*320*2      = 286720
  bf16*  Wm_bf = (bf16*)(ws + 286720);      //  320*320*2      = 204800 -> 491520
  float* b_all = (float*)(ws + 491520);     //  448*4          -> pad 493568
  bf16*  xT    = (bf16*)(ws + 493568);      //  4*4096*320*2   = 10485760 -> 10979328
  float* QK    = (float*)(ws + 10979328);   //  4*128*4096*4   = 8388608  -> 19367936
  bf16*  Qn    = (bf16*)(ws + 19367936);    //  8*4096*32*2    = 2097152  -> 21465088
  bf16*  Kn    = (bf16*)(ws + 21465088);    //  2097152        -> 23562240
  bf16*  Vc    = (bf16*)(ws + 23562240);    //  8*128*10*512*2 = 10485760 -> 34048000
  bf16*  Rt    = (bf16*)(ws + 34048000);    //  4*4096*320*2   = 10485760 -> 44533760

  k_prep<<<560, 256, 0, stream>>>(Wq, bq, Wk, bk, Wv, bv, Wm, W_all, Wm_bf, b_all);
  k_xt<<<2560, 256, 0, stream>>>(x, xT);
  k_proj<<<1792, 256, 0, stream>>>(W_all, b_all, xT, QK, Vc);
  k_norm<<<256, 256, 0, stream>>>(QK, Qn, Kn);
  k_attn<<<1024, 256, 0, stream>>>(Qn, Kn, Vc, Rt);
  k_merge<<<1280, 256, 0, stream>>>(Wm_bf, bm, Rt, x, out);
}